// Round 1
// baseline (103.486 us; speedup 1.0000x reference)
//
#include <hip/hip_runtime.h>
#include <math.h>

#define D 64
#define C 22
#define NCHUNK 16
#define CHUNK 1024          // covers Nt=16384 exactly; INF-padded otherwise
#define TEMP_F 2.0f
#define KL_W_F 0.2f

// ---------------------------------------------------------------- teacher logits
__global__ void tlogits_kernel(const float* __restrict__ t_feat,
                               const float* __restrict__ Wt,   // [C][D]
                               const float* __restrict__ bt,   // [C]
                               float* __restrict__ t_logits,   // [Nt][C]
                               int Nt)
{
    __shared__ __align__(16) float w[C * D];
    __shared__ float b[C];
    for (int k = threadIdx.x; k < C * D; k += blockDim.x) w[k] = Wt[k];
    if (threadIdx.x < C) b[threadIdx.x] = bt[threadIdx.x];
    __syncthreads();

    int i = blockIdx.x * blockDim.x + threadIdx.x;
    if (i >= Nt) return;

    float4 f[D / 4];
    const float4* fr = reinterpret_cast<const float4*>(t_feat + (size_t)i * D);
#pragma unroll
    for (int k = 0; k < D / 4; ++k) f[k] = fr[k];

#pragma unroll
    for (int c = 0; c < C; ++c) {
        float acc = b[c];
        const float4* wr = reinterpret_cast<const float4*>(&w[c * D]);
#pragma unroll
        for (int k = 0; k < D / 4; ++k) {
            float4 wv = wr[k];
            acc = fmaf(f[k].x, wv.x, acc);
            acc = fmaf(f[k].y, wv.y, acc);
            acc = fmaf(f[k].z, wv.z, acc);
            acc = fmaf(f[k].w, wv.w, acc);
        }
        t_logits[(size_t)i * C + c] = acc;
    }
}

// ---------------------------------------------------------------- 1-NN (chunked)
__global__ void nn_kernel(const float* __restrict__ sc,   // [Ns][3]
                          const float* __restrict__ tc,   // [Nt][3]
                          float* __restrict__ cand_d2,    // [Ns][NCHUNK]
                          int*   __restrict__ cand_idx,   // [Ns][NCHUNK]
                          int Ns, int Nt)
{
    __shared__ float4 tl[CHUNK];
    const int chunk = blockIdx.y;
    const int base  = chunk * CHUNK;

    for (int j = threadIdx.x; j < CHUNK; j += blockDim.x) {
        int g = base + j;
        if (g < Nt) {
            float x = tc[(size_t)g * 3 + 0];
            float y = tc[(size_t)g * 3 + 1];
            float z = tc[(size_t)g * 3 + 2];
            float t2 = x * x + y * y + z * z;
            tl[j] = make_float4(x, y, z, t2);
        } else {
            tl[j] = make_float4(0.f, 0.f, 0.f, INFINITY);
        }
    }
    __syncthreads();

    int i = blockIdx.x * blockDim.x + threadIdx.x;
    if (i >= Ns) return;

    float sx = sc[(size_t)i * 3 + 0];
    float sy = sc[(size_t)i * 3 + 1];
    float sz = sc[(size_t)i * 3 + 2];

    float best = INFINITY;
    int   bidx = base;
#pragma unroll 4
    for (int j = 0; j < CHUNK; ++j) {
        float4 t = tl[j];
        float dot = sx * t.x;
        dot = fmaf(sy, t.y, dot);
        dot = fmaf(sz, t.z, dot);
        // d2 minus the per-student constant |s|^2 — same argmin ordering
        float val = fmaf(dot, -2.0f, t.w);
        if (val < best) { best = val; bidx = base + j; }   // strict <: first-min
    }
    cand_d2[(size_t)i * NCHUNK + chunk] = best;
    cand_idx[(size_t)i * NCHUNK + chunk] = bidx;
}

// ---------------------------------------------------------------- per-student loss
__global__ void loss_kernel(const float* __restrict__ s_feat,   // [Ns][D]
                            const float* __restrict__ Ws,       // [C][D]
                            const float* __restrict__ bs_,      // [C]
                            const int*   __restrict__ segment,  // [Ns]
                            const float* __restrict__ t_logits, // [Nt][C]
                            const float* __restrict__ cand_d2,
                            const int*   __restrict__ cand_idx,
                            float* __restrict__ acc,            // [0]=seg_sum [1]=kl_sum
                            int Ns)
{
    __shared__ __align__(16) float w[C * D];
    __shared__ float b[C];
    __shared__ float red_seg[4], red_kl[4];
    for (int k = threadIdx.x; k < C * D; k += blockDim.x) w[k] = Ws[k];
    if (threadIdx.x < C) b[threadIdx.x] = bs_[threadIdx.x];
    __syncthreads();

    int i = blockIdx.x * blockDim.x + threadIdx.x;
    float seg_i = 0.f, kl_i = 0.f;

    if (i < Ns) {
        // reduce NN candidates (chunk-ascending, strict < keeps first occurrence)
        float best = cand_d2[(size_t)i * NCHUNK];
        int   bidx = cand_idx[(size_t)i * NCHUNK];
#pragma unroll
        for (int k = 1; k < NCHUNK; ++k) {
            float v = cand_d2[(size_t)i * NCHUNK + k];
            int   x = cand_idx[(size_t)i * NCHUNK + k];
            if (v < best) { best = v; bidx = x; }
        }

        // student logits
        float4 f[D / 4];
        const float4* fr = reinterpret_cast<const float4*>(s_feat + (size_t)i * D);
#pragma unroll
        for (int k = 0; k < D / 4; ++k) f[k] = fr[k];

        float l[C];
#pragma unroll
        for (int c = 0; c < C; ++c) {
            float a = b[c];
            const float4* wr = reinterpret_cast<const float4*>(&w[c * D]);
#pragma unroll
            for (int k = 0; k < D / 4; ++k) {
                float4 wv = wr[k];
                a = fmaf(f[k].x, wv.x, a);
                a = fmaf(f[k].y, wv.y, a);
                a = fmaf(f[k].z, wv.z, a);
                a = fmaf(f[k].w, wv.w, a);
            }
            l[c] = a;
        }

        float m1 = l[0];
#pragma unroll
        for (int c = 1; c < C; ++c) m1 = fmaxf(m1, l[c]);
        float sum1 = 0.f, sum2 = 0.f;
#pragma unroll
        for (int c = 0; c < C; ++c) {
            float d = l[c] - m1;
            sum1 += expf(d);
            sum2 += expf(0.5f * d);
        }
        float lse1 = logf(sum1);
        float lse2 = logf(sum2);

        int sg = segment[i];
        seg_i = -(l[sg] - m1 - lse1);

        // teacher side
        float t[C];
#pragma unroll
        for (int c = 0; c < C; ++c) t[c] = t_logits[(size_t)bidx * C + c];
        float mt = t[0];
#pragma unroll
        for (int c = 1; c < C; ++c) mt = fmaxf(mt, t[c]);
        float e[C];
        float den = 0.f;
#pragma unroll
        for (int c = 0; c < C; ++c) {
            e[c] = expf(0.5f * (t[c] - mt));
            den += e[c];
        }
        float logden = logf(den);
        float inv = 1.0f / den;

        float kls = 0.f;
#pragma unroll
        for (int c = 0; c < C; ++c) {
            float logtp = 0.5f * (t[c] - mt) - logden;   // log teacher_p
            float slp   = 0.5f * (l[c] - m1) - lse2;     // student log-softmax (T=2)
            kls = fmaf(e[c] * inv, logtp - slp, kls);
        }
        kl_i = kls;
    }

    // wave64 shuffle reduce, then cross-wave via LDS, one atomic per block
#pragma unroll
    for (int off = 32; off > 0; off >>= 1) {
        seg_i += __shfl_down(seg_i, off);
        kl_i  += __shfl_down(kl_i,  off);
    }
    int lane = threadIdx.x & 63;
    int wv   = threadIdx.x >> 6;
    if (lane == 0) { red_seg[wv] = seg_i; red_kl[wv] = kl_i; }
    __syncthreads();
    if (threadIdx.x == 0) {
        float s = red_seg[0] + red_seg[1] + red_seg[2] + red_seg[3];
        float k = red_kl[0] + red_kl[1] + red_kl[2] + red_kl[3];
        atomicAdd(&acc[0], s);
        atomicAdd(&acc[1], k);
    }
}

// ---------------------------------------------------------------- finalize
__global__ void finalize_kernel(const float* __restrict__ acc, float* __restrict__ out, int Ns)
{
    float seg_loss = acc[0] / (float)Ns;
    float kl_loss  = KL_W_F * (acc[1] / (float)Ns) * TEMP_F * TEMP_F;
    out[0] = seg_loss + kl_loss;
    out[1] = seg_loss;
    out[2] = kl_loss;
}

extern "C" void kernel_launch(void* const* d_in, const int* in_sizes, int n_in,
                              void* d_out, int out_size, void* d_ws, size_t ws_size,
                              hipStream_t stream)
{
    const float* s_feat  = (const float*)d_in[0];
    const float* t_feat  = (const float*)d_in[1];
    const float* s_coord = (const float*)d_in[2];
    const float* t_coord = (const float*)d_in[3];
    const float* seg_W   = (const float*)d_in[4];
    const float* seg_b   = (const float*)d_in[5];
    const float* seg_tW  = (const float*)d_in[6];
    const float* seg_tb  = (const float*)d_in[7];
    const int*   segment = (const int*)d_in[8];
    float* out = (float*)d_out;

    const int Ns = in_sizes[0] / D;
    const int Nt = in_sizes[1] / D;

    float* tlog    = (float*)d_ws;                       // [Nt*C]
    float* cand_d2 = tlog + (size_t)Nt * C;              // [Ns*NCHUNK]
    int*   cand_ix = (int*)(cand_d2 + (size_t)Ns * NCHUNK);
    float* acc     = (float*)(cand_ix + (size_t)Ns * NCHUNK);

    hipMemsetAsync(acc, 0, 2 * sizeof(float), stream);

    int nsb = (Ns + 255) / 256;
    int ntb = (Nt + 255) / 256;

    tlogits_kernel<<<ntb, 256, 0, stream>>>(t_feat, seg_tW, seg_tb, tlog, Nt);
    nn_kernel<<<dim3(nsb, NCHUNK), 256, 0, stream>>>(s_coord, t_coord, cand_d2, cand_ix, Ns, Nt);
    loss_kernel<<<nsb, 256, 0, stream>>>(s_feat, seg_W, seg_b, segment, tlog,
                                         cand_d2, cand_ix, acc, Ns);
    finalize_kernel<<<1, 1, 0, stream>>>(acc, out, Ns);
}